// Round 4
// baseline (818.481 us; speedup 1.0000x reference)
//
#include <hip/hip_runtime.h>

constexpr int N = 50000;        // nodes
constexpr int D = 64;           // feature dim
constexpr int E = 1600000;      // edges
constexpr int NBUCK = (N + 255) / 256;   // 196 buckets of 256 nodes (by dst>>8)
constexpr int CPT = 16;                  // edges per thread in k_bucket
constexpr int BUCK_BLOCKS = (E + 256 * CPT - 1) / (256 * CPT);  // 391

// ---------------------------------------------------------------------------
// K1: per-bucket edge histogram (LDS-privatized, one global atomic per bin/block)
__global__ void k_hist(const int* __restrict__ dst, int* __restrict__ ghist) {
    __shared__ int lh[NBUCK];
    int tid = threadIdx.x;
    for (int i = tid; i < NBUCK; i += 256) lh[i] = 0;
    __syncthreads();
    for (int e = blockIdx.x * 256 + tid; e < E; e += BUCK_BLOCKS * 256)
        atomicAdd(&lh[dst[e] >> 8], 1);
    __syncthreads();
    for (int i = tid; i < NBUCK; i += 256)
        if (lh[i]) atomicAdd(&ghist[i], lh[i]);
}

// K2: exclusive scan of the 196 bucket counts -> base[], cursor[]
__global__ void k_scan(const int* __restrict__ ghist, int* __restrict__ base,
                       int* __restrict__ cursor) {
    __shared__ int sm[256];
    int t = threadIdx.x;
    sm[t] = (t < NBUCK) ? ghist[t] : 0;
    __syncthreads();
    for (int off = 1; off < 256; off <<= 1) {
        int v = (t >= off) ? sm[t - off] : 0;
        __syncthreads();
        sm[t] += v;
        __syncthreads();
    }
    if (t < NBUCK) {
        int b = (t == 0) ? 0 : sm[t - 1];
        base[t] = b;
        cursor[t] = b;
    }
    if (t == 0) base[NBUCK] = E;
}

// K3: privatized counting-sort scatter into bucket-grouped packed edges.
// packed = (dst&255)<<16 | src  (src<50000 fits 16 bits, local fits 8).
// Per-(block,bucket) chunks are contiguous -> ~1x write amplification.
__global__ void k_bucket(const int* __restrict__ src, const int* __restrict__ dst,
                         int* __restrict__ cursor, unsigned* __restrict__ packed) {
    __shared__ int lh[NBUCK];
    __shared__ int lb[NBUCK];
    int tid = threadIdx.x;
    for (int i = tid; i < NBUCK; i += 256) lh[i] = 0;
    __syncthreads();
    int base_e = blockIdx.x * (256 * CPT);
    unsigned pk[CPT];
    int bn[CPT], rk[CPT];
#pragma unroll
    for (int i = 0; i < CPT; ++i) {
        int e = base_e + i * 256 + tid;
        if (e < E) {
            int d = dst[e];
            int s = src[e];
            bn[i] = d >> 8;
            pk[i] = ((unsigned)(d & 255) << 16) | (unsigned)s;
            rk[i] = atomicAdd(&lh[bn[i]], 1);
        } else bn[i] = -1;
    }
    __syncthreads();
    for (int i = tid; i < NBUCK; i += 256) {
        int c = lh[i];
        lb[i] = c ? atomicAdd(&cursor[i], c) : 0;
    }
    __syncthreads();
#pragma unroll
    for (int i = 0; i < CPT; ++i)
        if (bn[i] >= 0) packed[lb[bn[i]] + rk[i]] = pk[i];
}

// K4: per-bucket degree count in LDS -> norm (zero global atomics)
__global__ void k_degnorm(const int* __restrict__ base, const unsigned* __restrict__ packed,
                          float* __restrict__ norm) {
    __shared__ int cnt[256];
    int b = blockIdx.x;
    int tid = threadIdx.x;
    cnt[tid] = 0;
    __syncthreads();
    int beg = base[b], end = base[b + 1];
    for (int j = beg + tid; j < end; j += 256)
        atomicAdd(&cnt[(packed[j] >> 16) & 0xFF], 1);
    __syncthreads();
    int node = b * 256 + tid;
    if (node < N) norm[node] = cnt[tid] ? rsqrtf((float)cnt[tid]) : 0.0f;
}

// K5: h2[row][d] = (sum_k x[row][k] * W[k][d]) * norm[row]
// 1024 threads = 16 rows/block, W (16 KB) staged in LDS.
__global__ void k_gemm(const float* __restrict__ x, const float* __restrict__ W,
                       const float* __restrict__ norm, float* __restrict__ h2) {
    __shared__ float Wl[64 * 64];
    __shared__ float xs[16][64];
    int tid = threadIdx.x;
    const float4* W4 = (const float4*)W;
    float4* Wl4 = (float4*)Wl;
    for (int i = tid; i < 1024; i += 1024) Wl4[i] = W4[i];
    int r = tid >> 6, d = tid & 63;
    int row = blockIdx.x * 16 + r;
    xs[r][d] = x[row * 64 + d];
    __syncthreads();
    float a = 0.0f;
#pragma unroll
    for (int k = 0; k < 64; ++k) a = fmaf(xs[r][k], Wl[k * 64 + d], a);
    h2[row * 64 + d] = a * norm[row];
}

// K6: fused aggregate + dst-norm + bias + softplus.
// Block = (bucket, feature-quarter). LDS acc[256 nodes][16 feats] = 16 KB.
// 16-lane group per edge: one 64B line gathered per edge per block.
__global__ void k_agg(const int* __restrict__ base, const unsigned* __restrict__ packed,
                      const float* __restrict__ h2, const float* __restrict__ norm,
                      const float* __restrict__ bias, float* __restrict__ out) {
    __shared__ float acc[256 * 16];
    int bucket = blockIdx.x >> 2;
    int quarter = blockIdx.x & 3;
    int tid = threadIdx.x;
    for (int i = tid; i < 4096; i += 256) acc[i] = 0.0f;
    __syncthreads();
    int beg = base[bucket], end = base[bucket + 1];
    int f = tid & 15;
    int grp = tid >> 4;                     // 16 edge-groups per block
    const float* h2o = h2 + quarter * 16 + f;
    int j = beg + grp;
    for (; j + 16 < end; j += 32) {         // unroll x2 for MLP
        unsigned p0 = packed[j];
        unsigned p1 = packed[j + 16];
        float v0 = h2o[(p0 & 0xFFFFu) * 64];
        float v1 = h2o[(p1 & 0xFFFFu) * 64];
        atomicAdd(&acc[((p0 >> 16) & 0xFFu) * 16 + f], v0);
        atomicAdd(&acc[((p1 >> 16) & 0xFFu) * 16 + f], v1);
    }
    if (j < end) {
        unsigned p = packed[j];
        atomicAdd(&acc[((p >> 16) & 0xFFu) * 16 + f], h2o[(p & 0xFFFFu) * 64]);
    }
    __syncthreads();
    for (int i = tid; i < 4096; i += 256) {
        int local = i >> 4, f2 = i & 15;
        int node = bucket * 256 + local;
        if (node < N) {
            float v = acc[i] * norm[node] + bias[quarter * 16 + f2];
            out[node * 64 + quarter * 16 + f2] = fmaxf(v, 0.0f) + log1pf(expf(-fabsf(v)));
        }
    }
}

extern "C" void kernel_launch(void* const* d_in, const int* in_sizes, int n_in,
                              void* d_out, int out_size, void* d_ws, size_t ws_size,
                              hipStream_t stream) {
    // inputs: t(f32,1), x(f32,N*D), weight(f32,D*D), bias(f32,D), src(i32,E), dst(i32,E)
    const float* x    = (const float*)d_in[1];
    const float* W    = (const float*)d_in[2];
    const float* bias = (const float*)d_in[3];
    const int* src = (const int*)d_in[4];
    const int* dst = (const int*)d_in[5];
    float* out = (float*)d_out;

    // workspace layout (~19.4 MB; poisoned with 0xAA every call — all buffers
    // fully written before read)
    char* ws = (char*)d_ws;
    float*    h2     = (float*)(ws);                         // N*D f32 = 12.8 MB
    unsigned* packed = (unsigned*)(ws + 12800000);           // E u32  = 6.4 MB
    float*    norm   = (float*)(ws + 19200000);              // N f32
    int*      ghist  = (int*)(ws + 19400000);                // NBUCK
    int*      base   = (int*)(ws + 19400000 + 1024);         // NBUCK+1
    int*      cursor = (int*)(ws + 19400000 + 2048);         // NBUCK

    hipMemsetAsync(ghist, 0, NBUCK * sizeof(int), stream);

    k_hist   <<<BUCK_BLOCKS, 256, 0, stream>>>(dst, ghist);
    k_scan   <<<1, 256, 0, stream>>>(ghist, base, cursor);
    k_bucket <<<BUCK_BLOCKS, 256, 0, stream>>>(src, dst, cursor, packed);
    k_degnorm<<<NBUCK, 256, 0, stream>>>(base, packed, norm);
    k_gemm   <<<(N + 15) / 16, 1024, 0, stream>>>(x, W, norm, h2);
    k_agg    <<<NBUCK * 4, 256, 0, stream>>>(base, packed, h2, norm, bias, out);
}

// Round 5
// 227.758 us; speedup vs baseline: 3.5936x; 3.5936x over previous
//
#include <hip/hip_runtime.h>

constexpr int N = 50000;        // nodes
constexpr int D = 64;           // feature dim
constexpr int E = 1600000;      // edges
constexpr int NBUCK = (N + 255) / 256;   // 196 buckets of 256 nodes (dst>>8)
constexpr int CPT = 16;                  // edges per thread in k_bucket
constexpr int BUCK_BLOCKS = (E + 256 * CPT - 1) / (256 * CPT);  // 391

// ---------------------------------------------------------------------------
// K1: per-bucket edge histogram (LDS-privatized)
__global__ void k_hist(const int* __restrict__ dst, int* __restrict__ ghist) {
    __shared__ int lh[NBUCK];
    int tid = threadIdx.x;
    for (int i = tid; i < NBUCK; i += 256) lh[i] = 0;
    __syncthreads();
    for (int e = blockIdx.x * 256 + tid; e < E; e += BUCK_BLOCKS * 256)
        atomicAdd(&lh[dst[e] >> 8], 1);
    __syncthreads();
    for (int i = tid; i < NBUCK; i += 256)
        if (lh[i]) atomicAdd(&ghist[i], lh[i]);
}

// K2: exclusive scan of bucket counts -> base[], cursor[]
__global__ void k_scan(const int* __restrict__ ghist, int* __restrict__ base,
                       int* __restrict__ cursor) {
    __shared__ int sm[256];
    int t = threadIdx.x;
    sm[t] = (t < NBUCK) ? ghist[t] : 0;
    __syncthreads();
    for (int off = 1; off < 256; off <<= 1) {
        int v = (t >= off) ? sm[t - off] : 0;
        __syncthreads();
        sm[t] += v;
        __syncthreads();
    }
    if (t < NBUCK) {
        int b = (t == 0) ? 0 : sm[t - 1];
        base[t] = b;
        cursor[t] = b;
    }
    if (t == 0) base[NBUCK] = E;
}

// K3: privatized counting-sort scatter -> bucket-grouped packed edges.
// packed = (dst&255)<<16 | src  (src<65536, local dst<256).
__global__ void k_bucket(const int* __restrict__ src, const int* __restrict__ dst,
                         int* __restrict__ cursor, unsigned* __restrict__ packed) {
    __shared__ int lh[NBUCK];
    __shared__ int lb[NBUCK];
    int tid = threadIdx.x;
    for (int i = tid; i < NBUCK; i += 256) lh[i] = 0;
    __syncthreads();
    int base_e = blockIdx.x * (256 * CPT);
    unsigned pk[CPT];
    int bn[CPT], rk[CPT];
#pragma unroll
    for (int i = 0; i < CPT; ++i) {
        int e = base_e + i * 256 + tid;
        if (e < E) {
            int d = dst[e];
            int s = src[e];
            bn[i] = d >> 8;
            pk[i] = ((unsigned)(d & 255) << 16) | (unsigned)s;
            rk[i] = atomicAdd(&lh[bn[i]], 1);
        } else bn[i] = -1;
    }
    __syncthreads();
    for (int i = tid; i < NBUCK; i += 256) {
        int c = lh[i];
        lb[i] = c ? atomicAdd(&cursor[i], c) : 0;
    }
    __syncthreads();
#pragma unroll
    for (int i = 0; i < CPT; ++i)
        if (bn[i] >= 0) packed[lb[bn[i]] + rk[i]] = pk[i];
}

// K4: one block per bucket — local histogram + scan -> rowptr, norm, then
// scatter src (u16) into the bucket's own contiguous (L2-resident) CSR window.
__global__ void k_csr(const int* __restrict__ base, const unsigned* __restrict__ packed,
                      unsigned short* __restrict__ csr, int* __restrict__ rowptr,
                      float* __restrict__ norm) {
    __shared__ int cnt[256];
    __shared__ int sm[256];
    __shared__ int cur[256];
    int b = blockIdx.x, tid = threadIdx.x;
    cnt[tid] = 0;
    __syncthreads();
    int beg = base[b], end = base[b + 1];
    for (int j = beg + tid; j < end; j += 256)
        atomicAdd(&cnt[(packed[j] >> 16) & 0xFF], 1);
    __syncthreads();
    sm[tid] = cnt[tid];
    __syncthreads();
    for (int off = 1; off < 256; off <<= 1) {
        int v = (tid >= off) ? sm[tid - off] : 0;
        __syncthreads();
        sm[tid] += v;
        __syncthreads();
    }
    int excl = (tid == 0) ? 0 : sm[tid - 1];
    int node = b * 256 + tid;
    if (node < N) {
        rowptr[node] = beg + excl;
        norm[node] = cnt[tid] ? rsqrtf((float)cnt[tid]) : 0.0f;
    }
    if (b == 0 && tid == 0) rowptr[N] = E;
    cur[tid] = beg + excl;
    __syncthreads();
    for (int j = beg + tid; j < end; j += 256) {
        unsigned p = packed[j];
        int slot = atomicAdd(&cur[(p >> 16) & 0xFF], 1);
        csr[slot] = (unsigned short)(p & 0xFFFFu);
    }
}

// K5: h2[row][d] = (sum_k x[row][k] * W[k][d]) * norm[row]
__global__ void k_gemm(const float* __restrict__ x, const float* __restrict__ W,
                       const float* __restrict__ norm, float* __restrict__ h2) {
    __shared__ float Wl[64 * 64];
    __shared__ float xs[16][64];
    int tid = threadIdx.x;
    const float4* W4 = (const float4*)W;
    float4* Wl4 = (float4*)Wl;
    if (tid < 1024) Wl4[tid] = W4[tid];
    int r = tid >> 6, d = tid & 63;
    int row = blockIdx.x * 16 + r;
    xs[r][d] = x[row * 64 + d];
    __syncthreads();
    float a = 0.0f;
#pragma unroll
    for (int k = 0; k < 64; ++k) a = fmaf(xs[r][k], Wl[k * 64 + d], a);
    h2[row * 64 + d] = a * norm[row];
}

// K6: fused aggregate + dst-norm + bias + softplus.
// One wave per node, register accumulation, coalesced 256B row gathers,
// unroll x4 for memory-level parallelism. No atomics.
__global__ void k_aggregate(const int* __restrict__ rowptr,
                            const unsigned short* __restrict__ csr,
                            const float* __restrict__ h2, const float* __restrict__ norm,
                            const float* __restrict__ bias, float* __restrict__ out) {
    int node = blockIdx.x * 4 + (threadIdx.x >> 6);
    int lane = threadIdx.x & 63;
    if (node >= N) return;
    int beg = rowptr[node];
    int end = rowptr[node + 1];
    float a0 = 0.0f, a1 = 0.0f;
    int j = beg;
    for (; j + 3 < end; j += 4) {
        int s0 = csr[j];
        int s1 = csr[j + 1];
        int s2 = csr[j + 2];
        int s3 = csr[j + 3];
        float v0 = h2[s0 * 64 + lane];
        float v1 = h2[s1 * 64 + lane];
        float v2 = h2[s2 * 64 + lane];
        float v3 = h2[s3 * 64 + lane];
        a0 += v0 + v2;
        a1 += v1 + v3;
    }
    for (; j < end; ++j) a0 += h2[csr[j] * 64 + lane];
    float v = (a0 + a1) * norm[node] + bias[lane];
    out[node * 64 + lane] = fmaxf(v, 0.0f) + log1pf(expf(-fabsf(v)));
}

extern "C" void kernel_launch(void* const* d_in, const int* in_sizes, int n_in,
                              void* d_out, int out_size, void* d_ws, size_t ws_size,
                              hipStream_t stream) {
    // inputs: t(f32,1), x(f32,N*D), weight(f32,D*D), bias(f32,D), src(i32,E), dst(i32,E)
    const float* x    = (const float*)d_in[1];
    const float* W    = (const float*)d_in[2];
    const float* bias = (const float*)d_in[3];
    const int* src = (const int*)d_in[4];
    const int* dst = (const int*)d_in[5];
    float* out = (float*)d_out;

    // workspace layout (~23 MB; poisoned with 0xAA every call — every buffer
    // is fully written before it is read)
    char* ws = (char*)d_ws;
    float*          h2     = (float*)(ws);                       // 12.8 MB
    unsigned*       packed = (unsigned*)(ws + 12800000);         // 6.4 MB
    unsigned short* csr    = (unsigned short*)(ws + 19200000);   // 3.2 MB
    int*            rowptr = (int*)(ws + 22400000);              // (N+1)*4
    float*          norm   = (float*)(ws + 22600008);            // N*4
    int*            ghist  = (int*)(ws + 22800008);              // NBUCK
    int*            base   = (int*)(ws + 22800008 + 1024);       // NBUCK+1
    int*            cursor = (int*)(ws + 22800008 + 2048);       // NBUCK

    hipMemsetAsync(ghist, 0, NBUCK * sizeof(int), stream);

    k_hist     <<<BUCK_BLOCKS, 256, 0, stream>>>(dst, ghist);
    k_scan     <<<1, 256, 0, stream>>>(ghist, base, cursor);
    k_bucket   <<<BUCK_BLOCKS, 256, 0, stream>>>(src, dst, cursor, packed);
    k_csr      <<<NBUCK, 256, 0, stream>>>(base, packed, csr, rowptr, norm);
    k_gemm     <<<(N + 15) / 16, 1024, 0, stream>>>(x, W, norm, h2);
    k_aggregate<<<(N + 3) / 4, 256, 0, stream>>>(rowptr, csr, h2, norm, bias, out);
}

// Round 6
// 212.655 us; speedup vs baseline: 3.8489x; 1.0710x over previous
//
#include <hip/hip_runtime.h>
#include <hip/hip_fp16.h>

constexpr int N = 50000;        // nodes
constexpr int D = 64;           // feature dim
constexpr int E = 1600000;      // edges
constexpr int NBUCK = (N + 255) / 256;   // 196 buckets of 256 nodes (dst>>8)
constexpr int CPT = 16;                  // edges per thread in k_bucket
constexpr int BUCK_BLOCKS = (E + 256 * CPT - 1) / (256 * CPT);  // 391

// ---------------------------------------------------------------------------
// K1: per-bucket edge histogram (LDS-privatized)
__global__ void k_hist(const int* __restrict__ dst, int* __restrict__ ghist) {
    __shared__ int lh[NBUCK];
    int tid = threadIdx.x;
    for (int i = tid; i < NBUCK; i += 256) lh[i] = 0;
    __syncthreads();
    for (int e = blockIdx.x * 256 + tid; e < E; e += BUCK_BLOCKS * 256)
        atomicAdd(&lh[dst[e] >> 8], 1);
    __syncthreads();
    for (int i = tid; i < NBUCK; i += 256)
        if (lh[i]) atomicAdd(&ghist[i], lh[i]);
}

// K2: exclusive scan of bucket counts -> base[], cursor[]
__global__ void k_scan(const int* __restrict__ ghist, int* __restrict__ base,
                       int* __restrict__ cursor) {
    __shared__ int sm[256];
    int t = threadIdx.x;
    sm[t] = (t < NBUCK) ? ghist[t] : 0;
    __syncthreads();
    for (int off = 1; off < 256; off <<= 1) {
        int v = (t >= off) ? sm[t - off] : 0;
        __syncthreads();
        sm[t] += v;
        __syncthreads();
    }
    if (t < NBUCK) {
        int b = (t == 0) ? 0 : sm[t - 1];
        base[t] = b;
        cursor[t] = b;
    }
    if (t == 0) base[NBUCK] = E;
}

// K3: privatized counting-sort scatter -> bucket-grouped packed edges.
// packed = (dst&255)<<16 | src  (src<65536, local dst<256).
__global__ void k_bucket(const int* __restrict__ src, const int* __restrict__ dst,
                         int* __restrict__ cursor, unsigned* __restrict__ packed) {
    __shared__ int lh[NBUCK];
    __shared__ int lb[NBUCK];
    int tid = threadIdx.x;
    for (int i = tid; i < NBUCK; i += 256) lh[i] = 0;
    __syncthreads();
    int base_e = blockIdx.x * (256 * CPT);
    unsigned pk[CPT];
    int bn[CPT], rk[CPT];
#pragma unroll
    for (int i = 0; i < CPT; ++i) {
        int e = base_e + i * 256 + tid;
        if (e < E) {
            int d = dst[e];
            int s = src[e];
            bn[i] = d >> 8;
            pk[i] = ((unsigned)(d & 255) << 16) | (unsigned)s;
            rk[i] = atomicAdd(&lh[bn[i]], 1);
        } else bn[i] = -1;
    }
    __syncthreads();
    for (int i = tid; i < NBUCK; i += 256) {
        int c = lh[i];
        lb[i] = c ? atomicAdd(&cursor[i], c) : 0;
    }
    __syncthreads();
#pragma unroll
    for (int i = 0; i < CPT; ++i)
        if (bn[i] >= 0) packed[lb[bn[i]] + rk[i]] = pk[i];
}

// K4: one block (1024 thr) per bucket — local histogram + scan -> rowptr, norm,
// then scatter src (u16) into the bucket's contiguous L2-resident CSR window.
__global__ void k_csr(const int* __restrict__ base, const unsigned* __restrict__ packed,
                      unsigned short* __restrict__ csr, int* __restrict__ rowptr,
                      float* __restrict__ norm) {
    __shared__ int cnt[256];
    __shared__ int sm[256];
    __shared__ int cur[256];
    int b = blockIdx.x, tid = threadIdx.x;
    if (tid < 256) cnt[tid] = 0;
    __syncthreads();
    int beg = base[b], end = base[b + 1];
    for (int j = beg + tid; j < end; j += 1024)
        atomicAdd(&cnt[(packed[j] >> 16) & 0xFF], 1);
    __syncthreads();
    if (tid < 256) sm[tid] = cnt[tid];
    __syncthreads();
    for (int off = 1; off < 256; off <<= 1) {
        int v = 0;
        if (tid < 256 && tid >= off) v = sm[tid - off];
        __syncthreads();
        if (tid < 256) sm[tid] += v;
        __syncthreads();
    }
    if (tid < 256) {
        int excl = (tid == 0) ? 0 : sm[tid - 1];
        int node = b * 256 + tid;
        if (node < N) {
            rowptr[node] = beg + excl;
            norm[node] = cnt[tid] ? rsqrtf((float)cnt[tid]) : 0.0f;
        }
        if (b == 0 && tid == 0) rowptr[N] = E;
        cur[tid] = beg + excl;
    }
    __syncthreads();
    for (int j = beg + tid; j < end; j += 1024) {
        unsigned p = packed[j];
        int slot = atomicAdd(&cur[(p >> 16) & 0xFF], 1);
        csr[slot] = (unsigned short)(p & 0xFFFFu);
    }
}

// K5: h2[row][d] = (sum_k x[row][k] * W[k][d]) * norm[row], stored as fp16
__global__ void k_gemm(const float* __restrict__ x, const float* __restrict__ W,
                       const float* __restrict__ norm, __half* __restrict__ h2) {
    __shared__ float Wl[64 * 64];
    __shared__ float xs[16][64];
    int tid = threadIdx.x;
    const float4* W4 = (const float4*)W;
    float4* Wl4 = (float4*)Wl;
    if (tid < 1024) Wl4[tid] = W4[tid];
    int r = tid >> 6, d = tid & 63;
    int row = blockIdx.x * 16 + r;
    xs[r][d] = x[row * 64 + d];
    __syncthreads();
    float a = 0.0f;
#pragma unroll
    for (int k = 0; k < 64; ++k) a = fmaf(xs[r][k], Wl[k * 64 + d], a);
    h2[row * 64 + d] = __float2half(a * norm[row]);
}

// K6: fused aggregate + dst-norm + bias + softplus.
// One wave per node, register fp32 accumulation, 128B coalesced fp16 row
// gathers, unroll x4 for memory-level parallelism. No atomics.
__global__ void k_aggregate(const int* __restrict__ rowptr,
                            const unsigned short* __restrict__ csr,
                            const __half* __restrict__ h2, const float* __restrict__ norm,
                            const float* __restrict__ bias, float* __restrict__ out) {
    int node = blockIdx.x * 4 + (threadIdx.x >> 6);
    int lane = threadIdx.x & 63;
    if (node >= N) return;
    int beg = rowptr[node];
    int end = rowptr[node + 1];
    float a0 = 0.0f, a1 = 0.0f;
    int j = beg;
    for (; j + 3 < end; j += 4) {
        int s0 = csr[j];
        int s1 = csr[j + 1];
        int s2 = csr[j + 2];
        int s3 = csr[j + 3];
        float v0 = __half2float(h2[s0 * 64 + lane]);
        float v1 = __half2float(h2[s1 * 64 + lane]);
        float v2 = __half2float(h2[s2 * 64 + lane]);
        float v3 = __half2float(h2[s3 * 64 + lane]);
        a0 += v0 + v2;
        a1 += v1 + v3;
    }
    for (; j < end; ++j) a0 += __half2float(h2[csr[j] * 64 + lane]);
    float v = (a0 + a1) * norm[node] + bias[lane];
    out[node * 64 + lane] = fmaxf(v, 0.0f) + log1pf(expf(-fabsf(v)));
}

extern "C" void kernel_launch(void* const* d_in, const int* in_sizes, int n_in,
                              void* d_out, int out_size, void* d_ws, size_t ws_size,
                              hipStream_t stream) {
    // inputs: t(f32,1), x(f32,N*D), weight(f32,D*D), bias(f32,D), src(i32,E), dst(i32,E)
    const float* x    = (const float*)d_in[1];
    const float* W    = (const float*)d_in[2];
    const float* bias = (const float*)d_in[3];
    const int* src = (const int*)d_in[4];
    const int* dst = (const int*)d_in[5];
    float* out = (float*)d_out;

    // workspace layout (~16.5 MB; poisoned with 0xAA every call — every buffer
    // is fully written before it is read)
    char* ws = (char*)d_ws;
    __half*         h2     = (__half*)(ws);                      // 6.4 MB
    unsigned*       packed = (unsigned*)(ws + 6400000);          // 6.4 MB
    unsigned short* csr    = (unsigned short*)(ws + 12800000);   // 3.2 MB
    int*            rowptr = (int*)(ws + 16000000);              // (N+1)*4
    float*          norm   = (float*)(ws + 16200008);            // N*4
    int*            ghist  = (int*)(ws + 16400008);              // NBUCK
    int*            base   = (int*)(ws + 16400008 + 1024);       // NBUCK+1
    int*            cursor = (int*)(ws + 16400008 + 2048);       // NBUCK

    hipMemsetAsync(ghist, 0, NBUCK * sizeof(int), stream);

    k_hist     <<<BUCK_BLOCKS, 256, 0, stream>>>(dst, ghist);
    k_scan     <<<1, 256, 0, stream>>>(ghist, base, cursor);
    k_bucket   <<<BUCK_BLOCKS, 256, 0, stream>>>(src, dst, cursor, packed);
    k_csr      <<<NBUCK, 1024, 0, stream>>>(base, packed, csr, rowptr, norm);
    k_gemm     <<<(N + 15) / 16, 1024, 0, stream>>>(x, W, norm, h2);
    k_aggregate<<<(N + 3) / 4, 256, 0, stream>>>(rowptr, csr, h2, norm, bias, out);
}